// Round 1
// 2935.710 us; speedup vs baseline: 1.2104x; 1.2104x over previous
//
#include <hip/hip_runtime.h>
#include <stdint.h>

// LSTM: B=128, T=512, I=256, H=512.
// 8 groups (16 batches) x 32 WGs (16 h-cols) = 256 WGs, 1/CU.
// Weights [W|U] resident in VGPRs as MFMA B-frags (K-partitioned over 4 waves).
//
// R-new: TAGGED-DATA exchange. h is published as 64-bit atomic words:
//   lo32 = packed 2x bf16, hi32 = step tag. Consumers poll the data words
// directly for tag==t. This merges the old {h store -> vmcnt0 drain ->
// flag store -> flag poll -> h load} chain (≈2.5 L3 round trips + 2 extra
// __syncthreads) into a single fire-and-forget store + single polled load.
// Partial-order sync: each wave spins only on the K-columns it consumes
// (wave 3 = x-only never polls), so one straggler WG no longer gates the
// whole group through a full barrier.
// Overwrite safety (double-buffered hbuf): a WG publishes h(t+2) only after
// consuming all of h(t+1), which requires all WGs published h(t+1), which
// requires all WGs consumed h(t) -> no slot is overwritten before all reads.
// LDS partials are double-buffered so exactly ONE __syncthreads per step.

#define B_ 128
#define T_ 512
#define I_ 256
#define H_ 512
#define NB 16    // batches per group

using short8 = __attribute__((ext_vector_type(8))) short;
using f32x4  = __attribute__((ext_vector_type(4))) float;

union V16 {
  uint32_t u[4];
  uint64_t q[2];
  short8 s;
};

__device__ __forceinline__ unsigned short bf16rne(float f) {
  uint32_t u = __builtin_bit_cast(uint32_t, f);
  u += 0x7fffu + ((u >> 16) & 1u);
  return (unsigned short)(u >> 16);
}

__device__ __forceinline__ short8 cvt8(float4 a, float4 b) {
  short8 r;
  r[0] = (short)bf16rne(a.x); r[1] = (short)bf16rne(a.y);
  r[2] = (short)bf16rne(a.z); r[3] = (short)bf16rne(a.w);
  r[4] = (short)bf16rne(b.x); r[5] = (short)bf16rne(b.y);
  r[6] = (short)bf16rne(b.z); r[7] = (short)bf16rne(b.w);
  return r;
}

__global__ __launch_bounds__(256, 1) void lstm_fused(
    const float* __restrict__ x,
    const float* __restrict__ Wi, const float* __restrict__ Ui, const float* __restrict__ bi,
    const float* __restrict__ Wf, const float* __restrict__ Uf, const float* __restrict__ bfv,
    const float* __restrict__ Wo, const float* __restrict__ Uo, const float* __restrict__ bo,
    const float* __restrict__ Wc, const float* __restrict__ Uc, const float* __restrict__ bc,
    float* __restrict__ out, uint32_t* __restrict__ ws)
{
  const int bid   = blockIdx.x;
  const int group = bid & 7;        // XCD-locality heuristic only (not correctness)
  const int wg    = bid >> 3;       // 0..31 within group
  const int tid   = threadIdx.x;
  const int lane  = tid & 63;
  const int wave  = tid >> 6;       // 0..3
  const int quad  = lane >> 4;      // 0..3
  const int row16 = lane & 15;      // A: batch row / B: output col
  const int bg0   = group * NB;
  const int col0  = wg * 16;

  // hbuf: [2 buffers][128 batches][256 col-pairs] tagged 64-bit words.
  // word = (tag<<32) | (bf16(col 2c+1)<<16) | bf16(col 2c).  512 KB total.
  uint64_t* hbuf = (uint64_t*)ws;

  // partials: double-buffered [2][m*16+n][16 floats (w*4+g)], row stride 20
  // dwords => <=2-way bank aliasing (free) on both b128 store and read.
  __shared__ float part[2][256 * 20];

  const float* Wg[4] = {Wi, Wf, Wo, Wc};
  const float* Ug[4] = {Ui, Uf, Uo, Uc};

  // ---- resident B (weight) fragments: wave covers K in [wave*192, wave*192+192) ----
  // B-frag 16x16x32: lane holds B[k=quad*8+j][n=lane&15]; weights are [n][k] row-major.
  short8 bfr[6][4];
  const int kbase = wave * 192;
  #pragma unroll
  for (int ki = 0; ki < 6; ++ki) {
    const int kk = kbase + ki * 32;
    const int k  = kk + quad * 8;
    #pragma unroll
    for (int g = 0; g < 4; ++g) {
      const float* src = (kk < 512)
        ? (Wg[g] + (size_t)(col0 + row16) * H_ + k)
        : (Ug[g] + (size_t)(col0 + row16) * I_ + (k - 512));
      float4 lo = *(const float4*)src;
      float4 hi = *(const float4*)(src + 4);
      bfr[ki][g] = cvt8(lo, hi);
    }
  }

  // word index (sans buffer offset) for each h-carrying ki of this lane:
  // words cover cols [kk+quad*8, kk+quad*8+8) -> 4 consecutive 64b words.
  uint32_t hidx[6];
  #pragma unroll
  for (int ki = 0; ki < 6; ++ki) {
    const int kk = kbase + ki * 32;
    if (kk < 512)
      hidx[ki] = (uint32_t)(bg0 + row16) * 256u + (uint32_t)(kk >> 1) + (uint32_t)(quad << 2);
  }

  const int ub = tid >> 4;   // batch within group (update phase)
  const int uc = tid & 15;   // col within WG tile
  const float* bptr[4] = {bi, bfv, bo, bc};
  float bias[4];
  #pragma unroll
  for (int g = 0; g < 4; ++g) bias[g] = bptr[g][col0 + uc];

  float c_reg = 0.0f;

  for (int t = 0; t < T_; ++t) {
    // ---- prefetch x fragment (overlaps with the data poll below) ----
    short8 afrag[6];
    #pragma unroll
    for (int ki = 0; ki < 6; ++ki) {
      const int kk = kbase + ki * 32;
      if (kk >= 512) {
        const int k = kk + quad * 8;
        const float* xp = x + ((size_t)(bg0 + row16) * T_ + t) * I_ + (k - 512);
        float4 lo = *(const float4*)xp;
        float4 hi = *(const float4*)(xp + 4);
        afrag[ki] = cvt8(lo, hi);
      }
    }

    // ---- tagged-data poll: load h words, retry until all tags == t ----
    if (t > 0) {
      if (kbase < 512) {               // waves 0..2; wave 3 is x-only
        const uint32_t tgt = (uint32_t)t;
        uint64_t* hb = hbuf + (uint32_t)(t & 1) * 32768u;
        V16 hv[6];
        bool ok;
        do {
          uint32_t bad = 0;
          #pragma unroll
          for (int ki = 0; ki < 6; ++ki) {
            if (kbase + ki * 32 < 512) {
              uint64_t* p = hb + hidx[ki];
              uint64_t q0 = __hip_atomic_load(p + 0, __ATOMIC_RELAXED, __HIP_MEMORY_SCOPE_AGENT);
              uint64_t q1 = __hip_atomic_load(p + 1, __ATOMIC_RELAXED, __HIP_MEMORY_SCOPE_AGENT);
              uint64_t q2 = __hip_atomic_load(p + 2, __ATOMIC_RELAXED, __HIP_MEMORY_SCOPE_AGENT);
              uint64_t q3 = __hip_atomic_load(p + 3, __ATOMIC_RELAXED, __HIP_MEMORY_SCOPE_AGENT);
              hv[ki].u[0] = (uint32_t)q0; hv[ki].u[1] = (uint32_t)q1;
              hv[ki].u[2] = (uint32_t)q2; hv[ki].u[3] = (uint32_t)q3;
              bad |= ((uint32_t)(q0 >> 32) ^ tgt) | ((uint32_t)(q1 >> 32) ^ tgt)
                   | ((uint32_t)(q2 >> 32) ^ tgt) | ((uint32_t)(q3 >> 32) ^ tgt);
            }
          }
          ok = (bad == 0);
        } while (!__all((int)ok));
        #pragma unroll
        for (int ki = 0; ki < 6; ++ki)
          if (kbase + ki * 32 < 512) afrag[ki] = hv[ki].s;
      }
    } else {
      #pragma unroll
      for (int ki = 0; ki < 6; ++ki) {
        if (kbase + ki * 32 < 512) {
          V16 z; z.q[0] = 0; z.q[1] = 0;
          afrag[ki] = z.s;
        }
      }
    }

    // ---- MFMA: 6 K-iters x 4 gates ----
    f32x4 acc[4] = {{0.f,0.f,0.f,0.f},{0.f,0.f,0.f,0.f},
                    {0.f,0.f,0.f,0.f},{0.f,0.f,0.f,0.f}};
    #pragma unroll
    for (int ki = 0; ki < 6; ++ki) {
      #pragma unroll
      for (int g = 0; g < 4; ++g)
        acc[g] = __builtin_amdgcn_mfma_f32_16x16x32_bf16(afrag[ki], bfr[ki][g], acc[g], 0, 0, 0);
    }

    // ---- store partials transposed over gates: 4x b128, <=2-way banks ----
    // C/D layout: n = lane&15, m = quad*4 + reg.
    float* pb = part[t & 1];
    #pragma unroll
    for (int r = 0; r < 4; ++r) {
      f32x4 v;
      v[0] = acc[0][r]; v[1] = acc[1][r]; v[2] = acc[2][r]; v[3] = acc[3][r];
      *(f32x4*)&pb[(((quad << 2) + r) * 16 + row16) * 20 + (wave << 2)] = v;
    }
    __syncthreads();   // the ONLY barrier per step (part is double-buffered)

    // ---- reduce: thread tid handles (m=ub, n=uc); row = tid; 4x b128 reads ----
    const int rbase = tid * 20;
    f32x4 v0 = *(const f32x4*)&pb[rbase];
    f32x4 v1 = *(const f32x4*)&pb[rbase + 4];
    f32x4 v2 = *(const f32x4*)&pb[rbase + 8];
    f32x4 v3 = *(const f32x4*)&pb[rbase + 12];
    float pre[4];
    #pragma unroll
    for (int g = 0; g < 4; ++g)
      pre[g] = bias[g] + v0[g] + v1[g] + v2[g] + v3[g];

    const float ig = 1.0f / (1.0f + __expf(-pre[0]));
    const float fg = 1.0f / (1.0f + __expf(-pre[1]));
    const float og = 1.0f / (1.0f + __expf(-pre[2]));
    const float e2  = __expf(2.0f * pre[3]);
    const float ct  = (e2 - 1.0f) / (e2 + 1.0f);
    c_reg = fg * c_reg + ig * ct;
    const float e2c = __expf(2.0f * c_reg);
    const float tc  = (e2c - 1.0f) / (e2c + 1.0f);
    const float h   = og * tc;

    if (t < T_ - 1) {
      // publish: single tagged 64-bit atomic store, fire-and-forget.
      // (no vmcnt drain, no flag, no barrier — consumers poll the tag.)
      const float hpart = __shfl_xor(h, 1);
      if ((uc & 1) == 0) {
        const uint32_t d = (uint32_t)bf16rne(h) | ((uint32_t)bf16rne(hpart) << 16);
        const uint64_t qv = (uint64_t)d | ((uint64_t)(uint32_t)(t + 1) << 32);
        const uint32_t idx = (uint32_t)((t + 1) & 1) * 32768u
                           + (uint32_t)(bg0 + ub) * 256u
                           + (uint32_t)((col0 + uc) >> 1);
        __hip_atomic_store(hbuf + idx, qv, __ATOMIC_RELAXED, __HIP_MEMORY_SCOPE_AGENT);
      }
    } else {
      __builtin_nontemporal_store(
          h, &out[(size_t)B_ * T_ * H_ + (size_t)(bg0 + ub) * H_ + (col0 + uc)]);  // h_T
    }

    // hidden-seq store AFTER publish; nontemporal so the 134 MB stream doesn't
    // evict x / hbuf from L3 (keeps poll+prefetch latency low).
    __builtin_nontemporal_store(
        h, &out[((size_t)(bg0 + ub) * T_ + t) * H_ + (col0 + uc)]);
  }

  // c_T
  __builtin_nontemporal_store(
      c_reg, &out[(size_t)B_ * T_ * H_ + (size_t)B_ * H_ + (size_t)(bg0 + ub) * H_ + (col0 + uc)]);
}

extern "C" void kernel_launch(void* const* d_in, const int* in_sizes, int n_in,
                              void* d_out, int out_size, void* d_ws, size_t ws_size,
                              hipStream_t stream) {
  // ws layout: [0, 512KB): double-buffered tagged h exchange
  //            [2][128][256] x 8B words (tag in hi32; zeroed each launch so
  //            stale tags can never match t>=1).
  hipMemsetAsync(d_ws, 0, 2 * 128 * 256 * 8, stream);
  dim3 grid(256), block(256);
  lstm_fused<<<grid, block, 0, stream>>>(
      (const float*)d_in[0],
      (const float*)d_in[1], (const float*)d_in[2], (const float*)d_in[3],
      (const float*)d_in[4], (const float*)d_in[5], (const float*)d_in[6],
      (const float*)d_in[7], (const float*)d_in[8], (const float*)d_in[9],
      (const float*)d_in[10], (const float*)d_in[11], (const float*)d_in[12],
      (float*)d_out, (uint32_t*)d_ws);
}

// Round 2
// 2534.451 us; speedup vs baseline: 1.4020x; 1.1583x over previous
//
#include <hip/hip_runtime.h>
#include <stdint.h>

// LSTM: B=128, T=512, I=256, H=512.
// 8 groups (16 batches) x 32 WGs (16 h-cols) = 256 WGs, 1/CU.
// Weights [W|U] resident in VGPRs as MFMA B-frags (K-partitioned over 4 waves).
//
// R2: anti-flood exchange. Same tagged-data scheme as R1 (64b word =
// tag<<32 | 2x bf16; consumers poll the data itself), plus two fixes for
// L3 poll congestion (theory: 768 spinning waves x ~700 L3 txn/pass was
// queueing-delaying the fabric into a 13k-cycle step period):
//  (a) exchange layout transposed to [colpair][batch]: a quad-group's 16
//      lanes read 16 CONSECUTIVE batches at one colpair -> 128B contiguous
//      (2 lines) per load instead of 16 scattered 2KB-apart lines. ~4x
//      fewer transactions per poll pass.
//  (b) s_sleep(2) backoff between failed poll passes (~128cy): first pass
//      immediate (common case), retries rate-limited. ~5-8x fewer passes.
// Overwrite safety unchanged: double-buffered hbuf + all-consume-before-
// next-publish induction. ONE __syncthreads per step (LDS partials dbuf'd).

#define B_ 128
#define T_ 512
#define I_ 256
#define H_ 512
#define NB 16    // batches per group

using short8 = __attribute__((ext_vector_type(8))) short;
using f32x4  = __attribute__((ext_vector_type(4))) float;

union V16 {
  uint32_t u[4];
  uint64_t q[2];
  short8 s;
};

__device__ __forceinline__ unsigned short bf16rne(float f) {
  uint32_t u = __builtin_bit_cast(uint32_t, f);
  u += 0x7fffu + ((u >> 16) & 1u);
  return (unsigned short)(u >> 16);
}

__device__ __forceinline__ short8 cvt8(float4 a, float4 b) {
  short8 r;
  r[0] = (short)bf16rne(a.x); r[1] = (short)bf16rne(a.y);
  r[2] = (short)bf16rne(a.z); r[3] = (short)bf16rne(a.w);
  r[4] = (short)bf16rne(b.x); r[5] = (short)bf16rne(b.y);
  r[6] = (short)bf16rne(b.z); r[7] = (short)bf16rne(b.w);
  return r;
}

__global__ __launch_bounds__(256, 1) void lstm_fused(
    const float* __restrict__ x,
    const float* __restrict__ Wi, const float* __restrict__ Ui, const float* __restrict__ bi,
    const float* __restrict__ Wf, const float* __restrict__ Uf, const float* __restrict__ bfv,
    const float* __restrict__ Wo, const float* __restrict__ Uo, const float* __restrict__ bo,
    const float* __restrict__ Wc, const float* __restrict__ Uc, const float* __restrict__ bc,
    float* __restrict__ out, uint32_t* __restrict__ ws)
{
  const int bid   = blockIdx.x;
  const int group = bid & 7;        // XCD-locality heuristic only (not correctness)
  const int wg    = bid >> 3;       // 0..31 within group
  const int tid   = threadIdx.x;
  const int lane  = tid & 63;
  const int wave  = tid >> 6;       // 0..3
  const int quad  = lane >> 4;      // 0..3
  const int row16 = lane & 15;      // A: batch row / B: output col
  const int bg0   = group * NB;
  const int col0  = wg * 16;

  // hbuf: [2 buffers][256 colpairs][128 batches] tagged 64-bit words.
  // word = (tag<<32) | (bf16(col 2c+1)<<16) | bf16(col 2c).  512 KB total.
  // TRANSPOSED vs R1 so consumer quad-groups read contiguous batch runs.
  uint64_t* hbuf = (uint64_t*)ws;

  // partials: double-buffered [2][m*16+n][16 floats (w*4+g)], row stride 20
  // dwords => <=2-way bank aliasing (free) on both b128 store and read.
  __shared__ float part[2][256 * 20];

  const float* Wg[4] = {Wi, Wf, Wo, Wc};
  const float* Ug[4] = {Ui, Uf, Uo, Uc};

  // ---- resident B (weight) fragments: wave covers K in [wave*192, wave*192+192) ----
  // B-frag 16x16x32: lane holds B[k=quad*8+j][n=lane&15]; weights are [n][k] row-major.
  short8 bfr[6][4];
  const int kbase = wave * 192;
  #pragma unroll
  for (int ki = 0; ki < 6; ++ki) {
    const int kk = kbase + ki * 32;
    const int k  = kk + quad * 8;
    #pragma unroll
    for (int g = 0; g < 4; ++g) {
      const float* src = (kk < 512)
        ? (Wg[g] + (size_t)(col0 + row16) * H_ + k)
        : (Ug[g] + (size_t)(col0 + row16) * I_ + (k - 512));
      float4 lo = *(const float4*)src;
      float4 hi = *(const float4*)(src + 4);
      bfr[ki][g] = cvt8(lo, hi);
    }
  }

  // word index (sans buffer offset) for each h-carrying ki of this lane:
  // lane needs cols kk+quad*8 .. +8 = colpairs kk/2+quad*4 + {0,1,2,3},
  // each at word (colpair*128 + batch); the 4 words are 128 words apart.
  uint32_t hidx[6];
  #pragma unroll
  for (int ki = 0; ki < 6; ++ki) {
    const int kk = kbase + ki * 32;
    if (kk < 512)
      hidx[ki] = ((uint32_t)(kk >> 1) + (uint32_t)(quad << 2)) * 128u
               + (uint32_t)(bg0 + row16);
  }

  const int ub = tid >> 4;   // batch within group (update phase)
  const int uc = tid & 15;   // col within WG tile
  const float* bptr[4] = {bi, bfv, bo, bc};
  float bias[4];
  #pragma unroll
  for (int g = 0; g < 4; ++g) bias[g] = bptr[g][col0 + uc];

  float c_reg = 0.0f;

  for (int t = 0; t < T_; ++t) {
    // ---- prefetch x fragment (overlaps with the data poll below) ----
    short8 afrag[6];
    #pragma unroll
    for (int ki = 0; ki < 6; ++ki) {
      const int kk = kbase + ki * 32;
      if (kk >= 512) {
        const int k = kk + quad * 8;
        const float* xp = x + ((size_t)(bg0 + row16) * T_ + t) * I_ + (k - 512);
        float4 lo = *(const float4*)xp;
        float4 hi = *(const float4*)(xp + 4);
        afrag[ki] = cvt8(lo, hi);
      }
    }

    // ---- tagged-data poll: load h words, retry (w/ backoff) until tags == t ----
    if (t > 0) {
      if (kbase < 512) {               // waves 0..2; wave 3 is x-only
        const uint32_t tgt = (uint32_t)t;
        uint64_t* hb = hbuf + (uint32_t)(t & 1) * 32768u;
        V16 hv[6];
        bool ok;
        bool first = true;
        do {
          if (!first) __builtin_amdgcn_s_sleep(2);   // ~128cy backoff
          first = false;
          uint32_t bad = 0;
          #pragma unroll
          for (int ki = 0; ki < 6; ++ki) {
            if (kbase + ki * 32 < 512) {
              uint64_t* p = hb + hidx[ki];
              uint64_t q0 = __hip_atomic_load(p,       __ATOMIC_RELAXED, __HIP_MEMORY_SCOPE_AGENT);
              uint64_t q1 = __hip_atomic_load(p + 128, __ATOMIC_RELAXED, __HIP_MEMORY_SCOPE_AGENT);
              uint64_t q2 = __hip_atomic_load(p + 256, __ATOMIC_RELAXED, __HIP_MEMORY_SCOPE_AGENT);
              uint64_t q3 = __hip_atomic_load(p + 384, __ATOMIC_RELAXED, __HIP_MEMORY_SCOPE_AGENT);
              hv[ki].u[0] = (uint32_t)q0; hv[ki].u[1] = (uint32_t)q1;
              hv[ki].u[2] = (uint32_t)q2; hv[ki].u[3] = (uint32_t)q3;
              bad |= ((uint32_t)(q0 >> 32) ^ tgt) | ((uint32_t)(q1 >> 32) ^ tgt)
                   | ((uint32_t)(q2 >> 32) ^ tgt) | ((uint32_t)(q3 >> 32) ^ tgt);
            }
          }
          ok = (bad == 0);
        } while (!__all((int)ok));
        #pragma unroll
        for (int ki = 0; ki < 6; ++ki)
          if (kbase + ki * 32 < 512) afrag[ki] = hv[ki].s;
      }
    } else {
      #pragma unroll
      for (int ki = 0; ki < 6; ++ki) {
        if (kbase + ki * 32 < 512) {
          V16 z; z.q[0] = 0; z.q[1] = 0;
          afrag[ki] = z.s;
        }
      }
    }

    // ---- MFMA: 6 K-iters x 4 gates ----
    f32x4 acc[4] = {{0.f,0.f,0.f,0.f},{0.f,0.f,0.f,0.f},
                    {0.f,0.f,0.f,0.f},{0.f,0.f,0.f,0.f}};
    #pragma unroll
    for (int ki = 0; ki < 6; ++ki) {
      #pragma unroll
      for (int g = 0; g < 4; ++g)
        acc[g] = __builtin_amdgcn_mfma_f32_16x16x32_bf16(afrag[ki], bfr[ki][g], acc[g], 0, 0, 0);
    }

    // ---- store partials transposed over gates: 4x b128, <=2-way banks ----
    // C/D layout: n = lane&15, m = quad*4 + reg.
    float* pb = part[t & 1];
    #pragma unroll
    for (int r = 0; r < 4; ++r) {
      f32x4 v;
      v[0] = acc[0][r]; v[1] = acc[1][r]; v[2] = acc[2][r]; v[3] = acc[3][r];
      *(f32x4*)&pb[(((quad << 2) + r) * 16 + row16) * 20 + (wave << 2)] = v;
    }
    __syncthreads();   // the ONLY barrier per step (part is double-buffered)

    // ---- reduce: thread tid handles (m=ub, n=uc); row = tid; 4x b128 reads ----
    const int rbase = tid * 20;
    f32x4 v0 = *(const f32x4*)&pb[rbase];
    f32x4 v1 = *(const f32x4*)&pb[rbase + 4];
    f32x4 v2 = *(const f32x4*)&pb[rbase + 8];
    f32x4 v3 = *(const f32x4*)&pb[rbase + 12];
    float pre[4];
    #pragma unroll
    for (int g = 0; g < 4; ++g)
      pre[g] = bias[g] + v0[g] + v1[g] + v2[g] + v3[g];

    const float ig = 1.0f / (1.0f + __expf(-pre[0]));
    const float fg = 1.0f / (1.0f + __expf(-pre[1]));
    const float og = 1.0f / (1.0f + __expf(-pre[2]));
    const float e2  = __expf(2.0f * pre[3]);
    const float ct  = (e2 - 1.0f) / (e2 + 1.0f);
    c_reg = fg * c_reg + ig * ct;
    const float e2c = __expf(2.0f * c_reg);
    const float tc  = (e2c - 1.0f) / (e2c + 1.0f);
    const float h   = og * tc;

    if (t < T_ - 1) {
      // publish: single tagged 64-bit atomic store, fire-and-forget.
      const float hpart = __shfl_xor(h, 1);
      if ((uc & 1) == 0) {
        const uint32_t d = (uint32_t)bf16rne(h) | ((uint32_t)bf16rne(hpart) << 16);
        const uint64_t qv = (uint64_t)d | ((uint64_t)(uint32_t)(t + 1) << 32);
        const uint32_t idx = (uint32_t)((t + 1) & 1) * 32768u
                           + (uint32_t)((col0 + uc) >> 1) * 128u
                           + (uint32_t)(bg0 + ub);
        __hip_atomic_store(hbuf + idx, qv, __ATOMIC_RELAXED, __HIP_MEMORY_SCOPE_AGENT);
      }
    } else {
      __builtin_nontemporal_store(
          h, &out[(size_t)B_ * T_ * H_ + (size_t)(bg0 + ub) * H_ + (col0 + uc)]);  // h_T
    }

    // hidden-seq store AFTER publish; nontemporal so the 134 MB stream doesn't
    // evict x / hbuf from L3 (keeps poll+prefetch latency low).
    __builtin_nontemporal_store(
        h, &out[((size_t)(bg0 + ub) * T_ + t) * H_ + (col0 + uc)]);
  }

  // c_T
  __builtin_nontemporal_store(
      c_reg, &out[(size_t)B_ * T_ * H_ + (size_t)B_ * H_ + (size_t)(bg0 + ub) * H_ + (col0 + uc)]);
}

extern "C" void kernel_launch(void* const* d_in, const int* in_sizes, int n_in,
                              void* d_out, int out_size, void* d_ws, size_t ws_size,
                              hipStream_t stream) {
  // ws layout: [0, 512KB): double-buffered tagged h exchange
  //            [2][256 colpairs][128 batches] x 8B words (tag in hi32;
  //            zeroed each launch so stale tags can never match t>=1).
  hipMemsetAsync(d_ws, 0, 2 * 256 * 128 * 8, stream);
  dim3 grid(256), block(256);
  lstm_fused<<<grid, block, 0, stream>>>(
      (const float*)d_in[0],
      (const float*)d_in[1], (const float*)d_in[2], (const float*)d_in[3],
      (const float*)d_in[4], (const float*)d_in[5], (const float*)d_in[6],
      (const float*)d_in[7], (const float*)d_in[8], (const float*)d_in[9],
      (const float*)d_in[10], (const float*)d_in[11], (const float*)d_in[12],
      (float*)d_out, (uint32_t*)d_ws);
}